// Round 9
// baseline (283.513 us; speedup 1.0000x reference)
//
#include <hip/hip_runtime.h>
#include <math.h>

#define C      256
#define NPIX   196
#define BATCH  64
#define MAT    65536                  // C*C
#define OUTPB  32896                  // C*(C+1)/2

typedef _Float16 f16x8 __attribute__((ext_vector_type(8)));
typedef float    f32x4 __attribute__((ext_vector_type(4)));

// async 16B global->LDS; LDS base must be wave-uniform (HW adds lane*16)
__device__ __forceinline__ void gload16(const _Float16* g, _Float16* l) {
    __builtin_amdgcn_global_load_lds((const __attribute__((address_space(1))) void*)g,
                                     (__attribute__((address_space(3))) void*)l, 16, 0, 0);
}

// ---------------------------------------------------------------------------
// One full 256x256x256 fp16 MFMA matmul step, executed by ONE 1024-thread
// block (16 waves, 4x4 wave grid, 64x64 per wave). Double-buffered LDS
// (2 x 64KB: A[256x64] + B[256x64] panels), global_load_lds staging with
// pre-swizzled source columns, counted vmcnt(4) + raw s_barrier.
// Operand fragments use identical row addressing (all matrices symmetric).
// mode 0: O0 = A@B                mode 1: O0 = 1.5I - 0.5 A@B
// mode 2: outf = triu_packed(A@B * sqrt(ts/n))
// mode 3: O0 = A@B/ts ; O1 = 1.5I - 0.5*O0   (gram + prep)
// ---------------------------------------------------------------------------
__device__ __noinline__ void step_rt(int mode,
                                     const _Float16* __restrict__ Ap,
                                     const _Float16* __restrict__ Bp,
                                     _Float16* __restrict__ O0,
                                     _Float16* __restrict__ O1,
                                     float* __restrict__ outf,
                                     float ts) {
    __shared__ __align__(16) _Float16 lds[2][32768];   // 128 KB
    const int t = threadIdx.x;
    const int lane = t & 63, wid = t >> 6;
    const int wr = wid >> 2, wc = wid & 3;
    const int lr = lane & 15, lg = lane >> 4;

    f32x4 acc[4][4];
    const f32x4 zero = {0.f, 0.f, 0.f, 0.f};
    #pragma unroll
    for (int i = 0; i < 4; ++i)
        #pragma unroll
        for (int j = 0; j < 4; ++j) acc[i][j] = zero;

    // prologue: stage k0=0 into buffer 0 (4 chunks/thread, 16B each)
    #pragma unroll
    for (int cidx = 0; cidx < 4; ++cidx) {
        const int u = cidx * 1024 + t;
        const int plane = u >> 11, rr = (u >> 3) & 255, ch = u & 7;
        const _Float16* src = (plane ? Bp : Ap) + (size_t)rr * C + ((ch ^ (rr & 7)) << 3);
        gload16(src, &lds[0][0] + (size_t)(cidx * 1024 + wid * 64) * 8);
    }

    for (int ks = 0; ks < 4; ++ks) {
        const int cur = ks & 1;
        if (ks < 3) {
            #pragma unroll
            for (int cidx = 0; cidx < 4; ++cidx) {
                const int u = cidx * 1024 + t;
                const int plane = u >> 11, rr = (u >> 3) & 255, ch = u & 7;
                const _Float16* src = (plane ? Bp : Ap) + (size_t)rr * C
                                      + (ks + 1) * 64 + ((ch ^ (rr & 7)) << 3);
                gload16(src, &lds[cur ^ 1][0] + (size_t)(cidx * 1024 + wid * 64) * 8);
            }
            asm volatile("s_waitcnt vmcnt(4)" ::: "memory");   // cur buffer landed
        } else {
            asm volatile("s_waitcnt vmcnt(0)" ::: "memory");
        }
        __builtin_amdgcn_s_barrier();
        __builtin_amdgcn_sched_barrier(0);
        #pragma unroll
        for (int kk = 0; kk < 64; kk += 32) {
            f16x8 av[4];
            #pragma unroll
            for (int fi = 0; fi < 4; ++fi) {
                const int ra = wr * 64 + fi * 16 + lr;
                const int ca = ((kk >> 3) + lg) ^ (ra & 7);
                av[fi] = *(const f16x8*)&lds[cur][ra * 64 + ca * 8];
            }
            #pragma unroll
            for (int fj = 0; fj < 4; ++fj) {
                const int rb = wc * 64 + fj * 16 + lr;
                const int cb = ((kk >> 3) + lg) ^ (rb & 7);
                const f16x8 bv = *(const f16x8*)&lds[cur][16384 + rb * 64 + cb * 8];
                #pragma unroll
                for (int fi = 0; fi < 4; ++fi)
                    acc[fi][fj] = __builtin_amdgcn_mfma_f32_16x16x32_f16(av[fi], bv, acc[fi][fj], 0, 0, 0);
            }
        }
        __builtin_amdgcn_sched_barrier(0);
        __builtin_amdgcn_s_barrier();
    }

    // ---- epilogue ----
    const float invT  = 1.f / ts;
    const float scale = sqrtf(ts * (1.f / NPIX));
    #pragma unroll
    for (int fi = 0; fi < 4; ++fi) {
        #pragma unroll
        for (int fj = 0; fj < 4; ++fj) {
            #pragma unroll
            for (int q = 0; q < 4; ++q) {
                const int r_t = wr * 64 + fi * 16 + lg * 4 + q;
                const int c_t = wc * 64 + fj * 16 + lr;
                const float v = acc[fi][fj][q];
                if (mode == 0) {
                    O0[(size_t)r_t * C + c_t] = (_Float16)v;
                } else if (mode == 1) {
                    O0[(size_t)r_t * C + c_t] =
                        (_Float16)(((r_t == c_t) ? 1.5f : 0.f) - 0.5f * v);
                } else if (mode == 3) {
                    const float a = v * invT;
                    O0[(size_t)r_t * C + c_t] = (_Float16)a;
                    O1[(size_t)r_t * C + c_t] =
                        (_Float16)(((r_t == c_t) ? 1.5f : 0.f) - 0.5f * a);
                } else {   // mode 2
                    if (c_t >= r_t) {
                        const int off = r_t * C - (r_t * (r_t - 1)) / 2 - r_t + c_t;
                        outf[off] = v * scale;
                    }
                }
            }
        }
    }
    // drain stores; next step (or kernel end) reads them via L2
    asm volatile("s_waitcnt vmcnt(0)" ::: "memory");
    __builtin_amdgcn_s_barrier();
}

// ---------------------------------------------------------------------------
// One block per batch (64 blocks x 1024 threads, 1 block/CU).
// Preamble: center rows, convert fp16 (pad K 196->256), block-local trace.
// Then the entire 13-step Newton-Schulz chain with only intra-block sync.
// Slots P0..P4 (128 KB each) rotate; P4 holds centered xc initially.
// ---------------------------------------------------------------------------
__global__ __launch_bounds__(1024, 4) void chain_k(const float* __restrict__ x,
                                                   _Float16* __restrict__ ws,
                                                   float* __restrict__ outf) {
    const int b = blockIdx.x;
    const int t = threadIdx.x;
    const int lane = t & 63, wid = t >> 6;
    __shared__ float sred[16];

    _Float16* base = ws + (size_t)b * 5 * MAT;
    _Float16* P0 = base;
    _Float16* P1 = base + 1 * MAT;
    _Float16* P2 = base + 2 * MAT;
    _Float16* P3 = base + 3 * MAT;
    _Float16* P4 = base + 4 * MAT;   // xc

    // ---- preamble: centering + fp16 convert + trace ----
    float sqacc = 0.f;
    #pragma unroll 1
    for (int i = 0; i < 16; ++i) {
        const int r = wid * 16 + i;
        const float* xr = x + ((size_t)b * C + r) * NPIX;
        float v[4];
        float s = 0.f;
        #pragma unroll
        for (int j = 0; j < 4; ++j) {
            const int c = lane + (j << 6);
            v[j] = (c < NPIX) ? xr[c] : 0.f;
            s += v[j];
        }
        #pragma unroll
        for (int off = 32; off; off >>= 1) s += __shfl_xor(s, off, 64);
        const float mean = s * (1.f / NPIX);
        _Float16* o = P4 + (size_t)r * C;
        #pragma unroll
        for (int j = 0; j < 4; ++j) {
            const int c = lane + (j << 6);
            const float w = (c < NPIX) ? (v[j] - mean) : 0.f;
            sqacc += w * w;
            o[c] = (_Float16)w;
        }
    }
    #pragma unroll
    for (int off = 32; off; off >>= 1) sqacc += __shfl_xor(sqacc, off, 64);
    if (lane == 0) sred[wid] = sqacc;
    __syncthreads();                       // also drains xc stores (vmcnt 0)
    float ts = 0.f;
    #pragma unroll
    for (int i = 0; i < 16; ++i) ts += sred[i];

    // ---- 13-step chain ----
    step_rt(3, P4, P4, P0, P1, nullptr, ts);            // a->P0, z1->P1
    step_rt(0, P0, P1, P2, nullptr, nullptr, ts);       // y1 = a@z1      -> P2
    step_rt(1, P1, P2, P3, nullptr, nullptr, ts);       // bn1 = f(z1@y1) -> P3
    step_rt(0, P2, P3, P4, nullptr, nullptr, ts);       // y2 = y1@bn1    -> P4
    step_rt(0, P1, P3, P0, nullptr, nullptr, ts);       // z2 = z1@bn1    -> P0
    step_rt(1, P0, P4, P1, nullptr, nullptr, ts);       // bn2 = f(z2@y2) -> P1
    step_rt(0, P4, P1, P2, nullptr, nullptr, ts);       // y3 = y2@bn2    -> P2
    step_rt(0, P0, P1, P3, nullptr, nullptr, ts);       // z3 = z2@bn2    -> P3
    step_rt(1, P3, P2, P0, nullptr, nullptr, ts);       // bn3 = f(z3@y3) -> P0
    step_rt(0, P2, P0, P4, nullptr, nullptr, ts);       // y4 = y3@bn3    -> P4
    step_rt(0, P3, P0, P1, nullptr, nullptr, ts);       // z4 = z3@bn3    -> P1
    step_rt(1, P1, P4, P0, nullptr, nullptr, ts);       // bf = f(z4@y4)  -> P0
    step_rt(2, P4, P0, nullptr, nullptr,
            outf + (size_t)b * OUTPB, ts);              // out = triu(y4@bf * sqrt)
}

// ---------------------------------------------------------------------------
extern "C" void kernel_launch(void* const* d_in, const int* in_sizes, int n_in,
                              void* d_out, int out_size, void* d_ws, size_t ws_size,
                              hipStream_t stream) {
    const float* x = (const float*)d_in[0];
    float* out = (float*)d_out;
    _Float16* ws = (_Float16*)d_ws;
    chain_k<<<dim3(BATCH), dim3(1024), 0, stream>>>(x, ws, out);
}

// Round 11
// 156.118 us; speedup vs baseline: 1.8160x; 1.8160x over previous
//
#include <hip/hip_runtime.h>
#include <math.h>

#define C      256
#define NPIX   196
#define BATCH  64
#define MAT    65536                  // C*C
#define PLH    4194304                // BATCH*MAT (one fp16 plane, elements)
#define OUTPB  32896                  // C*(C+1)/2

typedef _Float16 f16x8 __attribute__((ext_vector_type(8)));
typedef float    f32x4 __attribute__((ext_vector_type(4)));

// async 16B global->LDS (LDS base wave-uniform; HW adds lane*16)
__device__ __forceinline__ void gload16(const _Float16* g, _Float16* l) {
    __builtin_amdgcn_global_load_lds((const __attribute__((address_space(1))) void*)g,
                                     (__attribute__((address_space(3))) void*)l, 16, 0, 0);
}

// ---------------------------------------------------------------------------
// convert: row-mean centering -> fp16, zero-pad K 196->256, per-row sum(xc^2).
// ---------------------------------------------------------------------------
__global__ __launch_bounds__(256) void convert_k(const float* __restrict__ x,
                                                 _Float16* __restrict__ xc,
                                                 float* __restrict__ rowsq) {
    const int bid = blockIdx.x;               // 4096 blocks
    const int xcd = bid & 7, j = bid >> 3;
    const int lb = j & 7, rc = j >> 3;
    const int b = xcd + (lb << 3);
    const int wave = threadIdx.x >> 6, lane = threadIdx.x & 63;
    const int row = rc * 4 + wave;
    const int rowg = b * 256 + row;
    const float* xr = x + (size_t)rowg * NPIX;
    float v[4];
    #pragma unroll
    for (int i = 0; i < 4; ++i) {
        int c = lane + (i << 6);
        v[i] = (c < NPIX) ? xr[c] : 0.f;
    }
    float s = v[0] + v[1] + v[2] + v[3];
    #pragma unroll
    for (int off = 32; off; off >>= 1) s += __shfl_xor(s, off, 64);
    const float mean = s * (1.f / NPIX);

    _Float16* o = xc + (size_t)b * MAT + (size_t)row * C;
    float sq = 0.f;
    #pragma unroll
    for (int i = 0; i < 4; ++i) {
        int c = lane + (i << 6);
        float w = (c < NPIX) ? (v[i] - mean) : 0.f;
        sq += w * w;
        o[c] = (_Float16)w;
    }
    #pragma unroll
    for (int off = 32; off; off >>= 1) sq += __shfl_xor(sq, off, 64);
    if (lane == 0) rowsq[rowg] = sq;
}

// ---------------------------------------------------------------------------
__global__ __launch_bounds__(256) void tracered_k(const float* __restrict__ rowsq,
                                                  float* __restrict__ trsum) {
    const int b = blockIdx.x, t = threadIdx.x;
    float v = rowsq[b * 256 + t];
    __shared__ float red[4];
    #pragma unroll
    for (int off = 32; off; off >>= 1) v += __shfl_xor(v, off, 64);
    if ((t & 63) == 0) red[t >> 6] = v;
    __syncthreads();
    if (t == 0) trsum[b] = red[0] + red[1] + red[2] + red[3];
}

// ---------------------------------------------------------------------------
// Batched 256x256x256 fp16 MFMA matmul, tile BM=BN=128, FULL-K staged once.
// 256 blocks (1/CU), 256 threads (4 waves, 2x2, wave tile 64x64 — the
// LDS-BW-balanced shape: 32 FLOP/LDS-byte > 26 needed). One vmcnt(0)+barrier
// per launch. Operand fragments use identical row addressing (symmetric).
// MODE 0: O = A@B          MODE 1: O = 1.5I - 0.5 A@B
// MODE 2: outf = triu_packed(A@B * sqrt(ts/n))
// MODE 3: O0 = A@B/ts ; O1 = 1.5I - 0.5*O0   (gram + prep)
// ---------------------------------------------------------------------------
template <int MODE>
__global__ __launch_bounds__(256, 1) void mm_k(const _Float16* __restrict__ A,
                                               const _Float16* __restrict__ Bop,
                                               _Float16* __restrict__ O0,
                                               _Float16* __restrict__ O1,
                                               float* __restrict__ outf,
                                               const float* __restrict__ trsum) {
    const int bid = blockIdx.x;
    const int xcd = bid & 7, j = bid >> 3;
    const int t4 = j & 3;
    const int bm = t4 >> 1, bn = t4 & 1;
    const int b = xcd + ((j >> 2) << 3);
    if (MODE == 2 && bm > bn) return;             // fully strictly-lower tile

    __shared__ __align__(16) _Float16 lds[65536]; // A[128][256] + B[128][256] = 128 KB

    const int t = threadIdx.x;
    const int lane = t & 63, wid = t >> 6;
    const int wr = wid >> 1, wc = wid & 1;
    const int lr = lane & 15, lg = lane >> 4;

    const size_t mb = (size_t)b * MAT;
    const _Float16* Ap = A + mb + (size_t)bm * 128 * C;
    const _Float16* Bp = Bop + mb + (size_t)bn * 128 * C;

    // ---- stage everything: 32 chunks/thread (16 A + 16 B), 16B each ----
    // chunk c in [0,4096) per panel: rr = c>>5, ch = c&31; src col-chunk is
    // pre-swizzled ch^(rr&7) (involution), LDS stays linear.
    #pragma unroll
    for (int i = 0; i < 16; ++i) {
        const int c = i * 256 + t;
        const int rr = c >> 5, ch = c & 31;
        gload16(Ap + (size_t)rr * C + ((ch ^ (rr & 7)) << 3),
                &lds[0] + (size_t)(i * 256 + wid * 64) * 8);
    }
    #pragma unroll
    for (int i = 0; i < 16; ++i) {
        const int c = i * 256 + t;
        const int rr = c >> 5, ch = c & 31;
        gload16(Bp + (size_t)rr * C + ((ch ^ (rr & 7)) << 3),
                &lds[32768] + (size_t)(i * 256 + wid * 64) * 8);
    }
    asm volatile("s_waitcnt vmcnt(0)" ::: "memory");
    __builtin_amdgcn_s_barrier();

    // ---- compute: 8 k-slices x (8 ds_read_b128 + 16 MFMA) per wave ----
    f32x4 acc[4][4];
    const f32x4 zero = {0.f, 0.f, 0.f, 0.f};
    #pragma unroll
    for (int i = 0; i < 4; ++i)
        #pragma unroll
        for (int jj = 0; jj < 4; ++jj) acc[i][jj] = zero;

    #pragma unroll
    for (int kk = 0; kk < 256; kk += 32) {
        f16x8 av[4], bv[4];
        #pragma unroll
        for (int fi = 0; fi < 4; ++fi) {
            const int ra = wr * 64 + fi * 16 + lr;
            const int ca = ((kk >> 3) + lg) ^ (ra & 7);
            av[fi] = *(const f16x8*)&lds[ra * 256 + ca * 8];
        }
        #pragma unroll
        for (int fj = 0; fj < 4; ++fj) {
            const int rb = wc * 64 + fj * 16 + lr;
            const int cb = ((kk >> 3) + lg) ^ (rb & 7);
            bv[fj] = *(const f16x8*)&lds[32768 + rb * 256 + cb * 8];
        }
        #pragma unroll
        for (int fi = 0; fi < 4; ++fi)
            #pragma unroll
            for (int fj = 0; fj < 4; ++fj)
                acc[fi][fj] = __builtin_amdgcn_mfma_f32_16x16x32_f16(av[fi], bv[fj], acc[fi][fj], 0, 0, 0);
    }

    // ---- epilogue ----
    float ts = 0.f;
    if (MODE == 2 || MODE == 3) ts = trsum[b];
    const float invT  = (MODE == 3) ? (1.f / ts) : 0.f;
    const float scale = (MODE == 2) ? sqrtf(ts * (1.f / NPIX)) : 0.f;

    #pragma unroll
    for (int fi = 0; fi < 4; ++fi) {
        #pragma unroll
        for (int fj = 0; fj < 4; ++fj) {
            #pragma unroll
            for (int q = 0; q < 4; ++q) {
                const int r_t = bm * 128 + wr * 64 + fi * 16 + lg * 4 + q;
                const int c_t = bn * 128 + wc * 64 + fj * 16 + lr;
                const float v = acc[fi][fj][q];
                if (MODE == 0) {
                    O0[mb + (size_t)r_t * C + c_t] = (_Float16)v;
                } else if (MODE == 1) {
                    O0[mb + (size_t)r_t * C + c_t] =
                        (_Float16)(((r_t == c_t) ? 1.5f : 0.f) - 0.5f * v);
                } else if (MODE == 3) {
                    const float a = v * invT;
                    O0[mb + (size_t)r_t * C + c_t] = (_Float16)a;
                    O1[mb + (size_t)r_t * C + c_t] =
                        (_Float16)(((r_t == c_t) ? 1.5f : 0.f) - 0.5f * a);
                } else if (MODE == 2) {
                    if (c_t >= r_t) {
                        const int off = r_t * C - (r_t * (r_t - 1)) / 2 - r_t + c_t;
                        outf[(size_t)b * OUTPB + off] = v * scale;
                    }
                }
            }
        }
    }
}

// ---------------------------------------------------------------------------
extern "C" void kernel_launch(void* const* d_in, const int* in_sizes, int n_in,
                              void* d_out, int out_size, void* d_ws, size_t ws_size,
                              hipStream_t stream) {
    const float* x = (const float*)d_in[0];
    float* out = (float*)d_out;
    _Float16* base = (_Float16*)d_ws;
    _Float16* P0 = base;
    _Float16* P1 = base + (size_t)1 * PLH;
    _Float16* P2 = base + (size_t)2 * PLH;
    _Float16* P3 = base + (size_t)3 * PLH;
    _Float16* P4 = base + (size_t)4 * PLH;   // xc
    float* trsum = (float*)(base + (size_t)5 * PLH);
    float* rowsq = trsum + 256;

    dim3 blk(256);
    dim3 g(256);

    convert_k<<<dim3(4096), blk, 0, stream>>>(x, P4, rowsq);
    tracered_k<<<dim3(64), blk, 0, stream>>>(rowsq, trsum);

    mm_k<3><<<g, blk, 0, stream>>>(P4, P4, P0, P1, nullptr, trsum);   // a->P0, z1->P1
    mm_k<0><<<g, blk, 0, stream>>>(P0, P1, P2, nullptr, nullptr, nullptr); // y1 -> P2
    mm_k<1><<<g, blk, 0, stream>>>(P1, P2, P3, nullptr, nullptr, nullptr); // bn1 -> P3
    mm_k<0><<<g, blk, 0, stream>>>(P2, P3, P4, nullptr, nullptr, nullptr); // y2 -> P4
    mm_k<0><<<g, blk, 0, stream>>>(P1, P3, P0, nullptr, nullptr, nullptr); // z2 -> P0
    mm_k<1><<<g, blk, 0, stream>>>(P0, P4, P1, nullptr, nullptr, nullptr); // bn2 -> P1
    mm_k<0><<<g, blk, 0, stream>>>(P4, P1, P2, nullptr, nullptr, nullptr); // y3 -> P2
    mm_k<0><<<g, blk, 0, stream>>>(P0, P1, P3, nullptr, nullptr, nullptr); // z3 -> P3
    mm_k<1><<<g, blk, 0, stream>>>(P3, P2, P0, nullptr, nullptr, nullptr); // bn3 -> P0
    mm_k<0><<<g, blk, 0, stream>>>(P2, P0, P4, nullptr, nullptr, nullptr); // y4 -> P4
    mm_k<0><<<g, blk, 0, stream>>>(P3, P0, P1, nullptr, nullptr, nullptr); // z4 -> P1
    mm_k<1><<<g, blk, 0, stream>>>(P1, P4, P0, nullptr, nullptr, nullptr); // bf -> P0
    mm_k<2><<<g, blk, 0, stream>>>(P4, P0, nullptr, nullptr, out, trsum); // out
}